// Round 6
// baseline (180.189 us; speedup 1.0000x reference)
//
#include <hip/hip_runtime.h>

// Multiresolution hash encoding, MI355X. Round 6: Morton-bucketed samples.
// Diagnosis: gather path is distinct-line-request bound (~0.24 lines/cyc/CU);
// uniform-random samples => full 64-way divergence per load. Fix: bucket
// samples by 12-bit Morton key (side-1/16 bricks, ~64 samples = 1 wave each)
// so a wave's lanes share corner entries at all res<=161 levels; TA coalesces
// same-line lanes to one transaction. Main compute body = R5 (pair-load via
// dim0 prime==1), reading sorted {x,y,z,sid} float4, scattering 128B rows.

constexpr int      kT    = 524288;       // 2^19 rows per level
constexpr unsigned kMask = kT - 1;
constexpr int      kB    = 262144;
constexpr unsigned kP1   = 2654435761u;
constexpr unsigned kP2   = 805459861u;
constexpr int      kBins = 4096;

typedef float f32x4 __attribute__((ext_vector_type(4)));

__device__ __forceinline__ unsigned morton12(float x0, float x1, float x2) {
    unsigned a = min(15u, (unsigned)(x0 * 16.0f));
    unsigned b = min(15u, (unsigned)(x1 * 16.0f));
    unsigned c = min(15u, (unsigned)(x2 * 16.0f));
    unsigned key = 0;
#pragma unroll
    for (int i = 3; i >= 0; --i)
        key = (key << 3) | (((a >> i) & 1u) << 2) | (((b >> i) & 1u) << 1) | ((c >> i) & 1u);
    return key;
}

__global__ __launch_bounds__(256) void hist_kernel(const float* __restrict__ x,
                                                   unsigned* __restrict__ hist) {
    const int i = blockIdx.x * 256 + threadIdx.x;
    const unsigned key = morton12(x[3 * i], x[3 * i + 1], x[3 * i + 2]);
    atomicAdd(&hist[key], 1u);
}

__global__ __launch_bounds__(1024) void scan_kernel(const unsigned* __restrict__ hist,
                                                    unsigned* __restrict__ cursor) {
    __shared__ unsigned part[1024];
    const int t = threadIdx.x;
    unsigned v[4], s = 0;
#pragma unroll
    for (int k = 0; k < 4; ++k) { v[k] = hist[t * 4 + k]; s += v[k]; }
    part[t] = s;
    __syncthreads();
    for (int off = 1; off < 1024; off <<= 1) {
        unsigned a = (t >= off) ? part[t - off] : 0u;
        __syncthreads();
        part[t] += a;
        __syncthreads();
    }
    unsigned excl = t ? part[t - 1] : 0u;
#pragma unroll
    for (int k = 0; k < 4; ++k) { cursor[t * 4 + k] = excl; excl += v[k]; }
}

__global__ __launch_bounds__(256) void scatter_kernel(const float* __restrict__ x,
                                                      unsigned* __restrict__ cursor,
                                                      f32x4* __restrict__ xsort) {
    const int i = blockIdx.x * 256 + threadIdx.x;
    const float x0 = x[3 * i], x1 = x[3 * i + 1], x2 = x[3 * i + 2];
    const unsigned key = morton12(x0, x1, x2);
    const unsigned slot = atomicAdd(&cursor[key], 1u);
    f32x4 v;
    v.x = x0; v.y = x1; v.z = x2; v.w = __uint_as_float((unsigned)i);
    xsort[slot] = v;  // keep in L2 (read back immediately by main kernel)
}

// ---- main compute body (R5 pair-load structure) ----
template <bool SORTED>
__device__ __forceinline__ void hashenc_body(const float x0, const float x1, const float x2,
                                             const f32x4* __restrict__ tab4base,
                                             f32x4* __restrict__ out, const unsigned sid) {
    f32x4 o[8];
    // floor(16 * b^l), b = 2^(1/3): rounding-traced, verified (absmax 4.8e-7)
    constexpr float kResF[16] = {16, 20, 25, 32, 40, 50, 64, 80,
                                 101, 128, 161, 203, 256, 322, 406, 512};
#pragma unroll
    for (int l = 0; l < 16; ++l) {
        const float res = kResF[l];
        const float s0 = x0 * res, s1 = x1 * res, s2 = x2 * res;
        const float f0 = floorf(s0), f1 = floorf(s1), f2 = floorf(s2);
        const float r0 = s0 - f0, r1 = s1 - f1, r2 = s2 - f2;
        const unsigned c0 = (unsigned)f0;
        const unsigned h1a = (unsigned)f1 * kP1, h1b = h1a + kP1;
        const unsigned h2a = (unsigned)f2 * kP2, h2b = h2a + kP2;
        const float w0a = 1.0f - r0, w1a = 1.0f - r1, w2a = 1.0f - r2;
        const f32x4* __restrict__ tab4 = tab4base + (size_t)l * (kT / 2);
        float a0 = 0.0f, a1 = 0.0f;
#pragma unroll
        for (int q = 0; q < 4; ++q) {  // (y,z) corner combos
            const unsigned g = ((q & 1) ? h1b : h1a) ^ ((q & 2) ? h2b : h2a);
            const unsigned i0 = (c0 ^ g) & kMask;
            const unsigned i1 = ((c0 + 1u) ^ g) & kMask;
            const f32x4 A = tab4[i0 >> 1];
            const f32x4 B = tab4[i1 >> 1];  // same line as A when c0 even
            const float p0x = (i0 & 1) ? A.z : A.x;
            const float p0y = (i0 & 1) ? A.w : A.y;
            const float p1x = (i1 & 1) ? B.z : B.x;
            const float p1y = (i1 & 1) ? B.w : B.y;
            const float wyz = ((q & 1) ? r1 : w1a) * ((q & 2) ? r2 : w2a);
            const float wl = wyz * w0a;
            const float wr = wyz * r0;
            a0 = fmaf(wl, p0x, fmaf(wr, p1x, a0));
            a1 = fmaf(wl, p0y, fmaf(wr, p1y, a1));
        }
        if (l & 1) { o[l >> 1].z = a0; o[l >> 1].w = a1; }
        else       { o[l >> 1].x = a0; o[l >> 1].y = a1; }
    }
    f32x4* op = out + (size_t)sid * 8;
#pragma unroll
    for (int k = 0; k < 8; ++k) __builtin_nontemporal_store(o[k], op + k);
}

__global__ __launch_bounds__(256, 4) void hashenc_sorted(const f32x4* __restrict__ xsort,
                                                         const f32x4* __restrict__ tab4base,
                                                         f32x4* __restrict__ out) {
    const int i = blockIdx.x * 256 + threadIdx.x;
    const f32x4 v = xsort[i];
    hashenc_body<true>(v.x, v.y, v.z, tab4base, out, __float_as_uint(v.w));
}

__global__ __launch_bounds__(256, 4) void hashenc_direct(const float* __restrict__ x,
                                                         const f32x4* __restrict__ tab4base,
                                                         f32x4* __restrict__ out) {
    const int i = blockIdx.x * 256 + threadIdx.x;
    hashenc_body<false>(x[3 * i], x[3 * i + 1], x[3 * i + 2], tab4base, out, (unsigned)i);
}

extern "C" void kernel_launch(void* const* d_in, const int* in_sizes, int n_in,
                              void* d_out, int out_size, void* d_ws, size_t ws_size,
                              hipStream_t stream) {
    const float*  x    = (const float*)d_in[0];
    const f32x4*  tab4 = (const f32x4*)d_in[1];
    f32x4*        out  = (f32x4*)d_out;

    const size_t histBytes   = (size_t)kBins * 4;
    const size_t cursorBytes = (size_t)kBins * 4;
    const size_t xsortBytes  = (size_t)kB * 16;
    const size_t need = histBytes + cursorBytes + xsortBytes;

    if (ws_size >= need) {
        unsigned* hist   = (unsigned*)d_ws;
        unsigned* cursor = (unsigned*)((char*)d_ws + histBytes);
        f32x4*    xsort  = (f32x4*)((char*)d_ws + histBytes + cursorBytes);
        hipMemsetAsync(hist, 0, histBytes, stream);
        hist_kernel<<<kB / 256, 256, 0, stream>>>(x, hist);
        scan_kernel<<<1, 1024, 0, stream>>>(hist, cursor);
        scatter_kernel<<<kB / 256, 256, 0, stream>>>(x, cursor, xsort);
        hashenc_sorted<<<kB / 256, 256, 0, stream>>>(xsort, tab4, out);
    } else {
        hashenc_direct<<<kB / 256, 256, 0, stream>>>(x, tab4, out);
    }
}